// Round 9
// baseline (1016.690 us; speedup 1.0000x reference)
//
#include <hip/hip_runtime.h>
#include <math.h>

#define NN 50000
#define EA 800000
#define EC 400000
#define EIN 600000
#define NG 128
#define FIN 54

#define DEV_VDW 0.2f
#define EPS_LO_ 0.0178f
#define EPS_HI_ 0.2f

typedef unsigned int uint;
typedef unsigned short ushort;
typedef unsigned long long ull;
typedef __attribute__((ext_vector_type(8))) short bf16x8;
typedef __attribute__((ext_vector_type(4))) float f32x4;

__device__ __forceinline__ ushort f2bf(float f){
  uint x = __float_as_uint(f);
  uint r = x + 0x7fffu + ((x >> 16) & 1u);
  return (ushort)(r >> 16);
}
__device__ __forceinline__ uint f2bf2(float a, float b){
  return (uint)f2bf(a) | ((uint)f2bf(b) << 16);
}
__device__ __forceinline__ void decode8(uint4 u, float* f){
  f[0] = __uint_as_float(u.x << 16); f[1] = __uint_as_float(u.x & 0xffff0000u);
  f[2] = __uint_as_float(u.y << 16); f[3] = __uint_as_float(u.y & 0xffff0000u);
  f[4] = __uint_as_float(u.z << 16); f[5] = __uint_as_float(u.z & 0xffff0000u);
  f[6] = __uint_as_float(u.w << 16); f[7] = __uint_as_float(u.w & 0xffff0000u);
}

// ---------------- CSR count ----------------
__global__ void k_count(const int* __restrict__ dstA, const int* __restrict__ dstC,
                        const int* __restrict__ dstI,
                        int* __restrict__ cntA, int* __restrict__ cntC, int* __restrict__ cntI){
  int b = blockIdx.x;
  const int* dst; int* cnt; int E; int bid; int nb;
  if (b < 1024){ dst = dstA; cnt = cntA; E = EA;  bid = b;        nb = 1024; }
  else if (b < 1536){ dst = dstC; cnt = cntC; E = EC;  bid = b - 1024; nb = 512; }
  else { dst = dstI; cnt = cntI; E = EIN; bid = b - 1536; nb = 1024; }
  for (int i = bid * 256 + threadIdx.x; i < E; i += nb * 256) atomicAdd(&cnt[dst[i]], 1);
}

__global__ void k_scan3(const int* __restrict__ cntA, int* __restrict__ offA, int* __restrict__ curA,
                        const int* __restrict__ cntC, int* __restrict__ offC, int* __restrict__ curC,
                        const int* __restrict__ cntI, int* __restrict__ offI, int* __restrict__ curI){
  const int* cnt = (blockIdx.x == 0) ? cntA : (blockIdx.x == 1) ? cntC : cntI;
  int* off = (blockIdx.x == 0) ? offA : (blockIdx.x == 1) ? offC : offI;
  int* cur = (blockIdx.x == 0) ? curA : (blockIdx.x == 1) ? curC : curI;
  int n = NN;
  __shared__ int wsums[16];
  __shared__ int run_s;
  int tid = threadIdx.x;            // 1024
  int lane = tid & 63, w = tid >> 6;
  if (tid == 0) run_s = 0;
  __syncthreads();
  for (int base = 0; base < n; base += 1024){
    int run = run_s;
    int i = base + tid;
    int v = (i < n) ? cnt[i] : 0;
    int s = v;
    #pragma unroll
    for (int o = 1; o < 64; o <<= 1){ int t = __shfl_up(s, o, 64); if (lane >= o) s += t; }
    if (lane == 63) wsums[w] = s;
    __syncthreads();
    if (w == 0 && lane < 16){
      int t = wsums[lane];
      #pragma unroll
      for (int o = 1; o < 16; o <<= 1){ int u = __shfl_up(t, o, 64); if (lane >= o) t += u; }
      wsums[lane] = t;
    }
    __syncthreads();
    int woff = (w == 0) ? 0 : wsums[w - 1];
    int excl = run + woff + (s - v);
    if (i < n){ off[i] = excl; cur[i] = excl; }
    int tot = wsums[15];
    __syncthreads();
    if (tid == 0) run_s = run + tot;
    __syncthreads();
  }
  if (threadIdx.x == 0) off[n] = run_s;
}

// ---------------- place: atomic slot + nontemporal scattered stores ----------------
__global__ void k_place(const int* __restrict__ eiA, const int* __restrict__ eiC,
                        const int* __restrict__ eiI,
                        int* __restrict__ curA, int* __restrict__ srcA,
                        int* __restrict__ curC, int* __restrict__ srcC,
                        int* __restrict__ curI, ull* __restrict__ jeI, int* __restrict__ iI){
  int b = blockIdx.x;
  if (b < 1024){
    for (int i = b * 256 + threadIdx.x; i < EA; i += 1024 * 256){
      int d = eiA[EA + i];
      int slot = atomicAdd(&curA[d], 1);
      __builtin_nontemporal_store(eiA[i], &srcA[slot]);
    }
  } else if (b < 1536){
    int bid = b - 1024;
    for (int i = bid * 256 + threadIdx.x; i < EC; i += 512 * 256){
      int d = eiC[EC + i];
      int slot = atomicAdd(&curC[d], 1);
      __builtin_nontemporal_store(eiC[i], &srcC[slot]);
    }
  } else {
    int bid = b - 1536;
    for (int i = bid * 256 + threadIdx.x; i < EIN; i += 1024 * 256){
      int key = eiI[i];                                  // group by i
      int slot = atomicAdd(&curI[key], 1);
      ull v = ((ull)(uint)i << 32) | (uint)eiI[EIN + i]; // hi=edge id, lo=j
      __builtin_nontemporal_store(v, &jeI[slot]);
      __builtin_nontemporal_store(key, &iI[slot]);
    }
  }
}

// ---------------- fused misc: prepw (blocks 0-13) + nodeinfo (14-209) + embed (210+) ----------------
// WT slots ([n][k] bf16): 0-2 gatW, 3-5 WA=gatW@gatA, 6-8 intW, 9-10 dw1, 11-12 ew1
// BIASALL[13][128]: 0-2 gatWb, 3-5 gatWb@gatA, 6-8 intWb, 9 db1, 10 zero, 11 eb1, 12 zero
__global__ __launch_bounds__(256) void k_misc(
                        const float* __restrict__ gatW, const float* __restrict__ gatA,
                        const float* __restrict__ intW, const float* __restrict__ dw1,
                        const float* __restrict__ ew1,
                        const float* __restrict__ gatWb, const float* __restrict__ intWb,
                        const float* __restrict__ db1, const float* __restrict__ eb1,
                        uint* __restrict__ Wt, float* __restrict__ BIASALL,
                        const float* __restrict__ POS, const float* __restrict__ RAD,
                        const int* __restrict__ Mmet, const int* __restrict__ Mdon,
                        const int* __restrict__ Macc, const int* __restrict__ Mhyd,
                        const int* __restrict__ BATCH,
                        float4* __restrict__ PRAD, uint* __restrict__ MB,
                        const float* __restrict__ X, const float* __restrict__ embW,
                        uint* __restrict__ Hh){
  __shared__ char SMEM[33792];
  int b = blockIdx.x;
  int tid = threadIdx.x;
  if (b >= 210){
    // ---- embed: 2 rows per iteration ----
    float* Wls = (float*)SMEM;   // 54*128*4 = 27648 B
    for (int i = tid; i < FIN * 128; i += 256) Wls[i] = embW[i];
    __syncthreads();
    int col = tid & 127, rh = tid >> 7;
    for (int row = (b - 210) * 2 + rh; row < NN; row += 4096){
      const float* xr = X + row * FIN;
      float acc = 0.f;
      #pragma unroll
      for (int k = 0; k < FIN; ++k) acc += xr[k] * Wls[k * 128 + col];
      ((ushort*)Hh)[(size_t)row * 128 + col] = f2bf(acc);
    }
    return;
  }
  if (b >= 14){
    int n = (b - 14) * 256 + tid;
    if (n < NN){
      PRAD[n] = make_float4(POS[3*n], POS[3*n+1], POS[3*n+2], RAD[n]);
      uint m = (Mmet[n] ? 1u : 0u) | (Mdon[n] ? 2u : 0u) | (Macc[n] ? 4u : 0u) |
               (Mhyd[n] ? 8u : 0u) | ((uint)BATCH[n] << 8);
      MB[n] = m;
    }
    return;
  }
  int m = b;
  ushort* L = (ushort*)SMEM;     // 128*132*2 = 33792 B
  if (m == 13){
    for (int idx = tid; idx < 13 * 128; idx += 256){
      int slot = idx >> 7, c = idx & 127;
      if (slot >= 3 && slot < 6) continue;   // written by WA blocks
      float v = 0.f;
      if (slot < 3) v = gatWb[slot * 128 + c];
      else if (slot < 9) v = intWb[(slot - 6) * 128 + c];
      else if (slot == 9) v = db1[c];
      else if (slot == 11) v = eb1[c];
      BIASALL[idx] = v;
    }
    return;
  }
  if (m >= 3 && m < 6){
    int l = m - 3;
    const float* Wf  = gatW + l * 16384;
    const float* Af  = gatA + l * 16384;
    const float* Wbf = gatWb + l * 128;
    for (int idx = tid; idx < 16384; idx += 256){
      int k = idx >> 7, n = idx & 127;
      L[k * 132 + n] = f2bf(Af[idx]);
    }
    __syncthreads();
    int r = tid >> 1, ch = tid & 1;
    float accv[64];
    #pragma unroll
    for (int c = 0; c < 64; ++c) accv[c] = 0.f;
    float accb = 0.f;
    int bc = tid & 127;
    for (int mm = 0; mm < 128; ++mm){
      float wv = Wf[r * 128 + mm];
      const uint* Lr32 = (const uint*)&L[mm * 132 + ch * 64];
      #pragma unroll
      for (int c2 = 0; c2 < 32; ++c2){
        uint u = Lr32[c2];
        accv[2 * c2]     += wv * __uint_as_float(u << 16);
        accv[2 * c2 + 1] += wv * __uint_as_float(u & 0xffff0000u);
      }
      accb += Wbf[mm] * __uint_as_float((uint)L[mm * 132 + bc] << 16);
    }
    __syncthreads();
    #pragma unroll
    for (int c = 0; c < 64; ++c) L[r * 132 + ch * 64 + c] = f2bf(accv[c]);
    if (tid < 128) BIASALL[(3 + l) * 128 + tid] = accb;
    __syncthreads();
    int n = tid & 127, half = tid >> 7;
    uint* outp = Wt + (size_t)m * 8192 + n * 64 + half * 32;
    #pragma unroll
    for (int kk2 = 0; kk2 < 32; ++kk2){
      int k = half * 64 + 2 * kk2;
      uint u = (uint)L[k * 132 + n] | ((uint)L[(k + 1) * 132 + n] << 16);
      outp[kk2] = u;
    }
    return;
  }
  const float* src = (m < 3)  ? gatW + m * 16384 :
                     (m < 9)  ? intW + (m - 6) * 16384 :
                     (m < 11) ? dw1 + (m - 9) * 16384 :
                                ew1 + (m - 11) * 16384;
  for (int idx = tid; idx < 16384; idx += 256){
    int k = idx >> 7, n = idx & 127;
    L[k * 132 + n] = f2bf(src[idx]);
  }
  __syncthreads();
  int n = tid & 127, half = tid >> 7;
  uint* outp = Wt + (size_t)m * 8192 + n * 64 + half * 32;
  #pragma unroll
  for (int kk2 = 0; kk2 < 32; ++kk2){
    int k = half * 64 + 2 * kk2;
    uint u = (uint)L[k * 132 + n] | ((uint)L[(k + 1) * 132 + n] << 16);
    outp[kk2] = u;
  }
}

// ---------------- MFMA GEMM with y-indexed (B, bias, C) sets ----------------
template<bool RELU>
__global__ __launch_bounds__(256) void k_gemm_mfma(const uint* __restrict__ Ah,
        const uint* __restrict__ Bt0, size_t strideB,
        const float* __restrict__ bias0, size_t strideBias,
        uint* __restrict__ C0, size_t strideC, int N){
  const uint* Bt = Bt0 + (size_t)blockIdx.y * strideB;
  const float* bias = bias0 + (size_t)blockIdx.y * strideBias;
  uint* Cout = C0 + (size_t)blockIdx.y * strideC;
  int tid = threadIdx.x;
  int lane = tid & 63;
  int wv = tid >> 6;                      // 0..3
  int row0 = blockIdx.x * 128 + wv * 32;
  int l15 = lane & 15, lg = lane >> 4;
  int ra0 = row0 + l15, ra1 = row0 + 16 + l15;
  const uint* pa0 = Ah + (size_t)(ra0 < N ? ra0 : 0) * 64 + lg * 4;
  const uint* pa1 = Ah + (size_t)(ra1 < N ? ra1 : 0) * 64 + lg * 4;
  const uint* pb  = Bt + (size_t)l15 * 64 + lg * 4;
  f32x4 acc[2][8] = {};
  #pragma unroll
  for (int c = 0; c < 4; ++c){
    bf16x8 a0 = *(const bf16x8*)(pa0 + c * 16);
    bf16x8 a1 = *(const bf16x8*)(pa1 + c * 16);
    #pragma unroll
    for (int ct = 0; ct < 8; ++ct){
      bf16x8 b = *(const bf16x8*)(pb + ct * 1024 + c * 16);
      acc[0][ct] = __builtin_amdgcn_mfma_f32_16x16x32_bf16(a0, b, acc[0][ct], 0, 0, 0);
      acc[1][ct] = __builtin_amdgcn_mfma_f32_16x16x32_bf16(a1, b, acc[1][ct], 0, 0, 0);
    }
  }
  #pragma unroll
  for (int ct = 0; ct < 8; ++ct){
    int col = ct * 16 + l15;
    float bv = bias[col];
    #pragma unroll
    for (int rt = 0; rt < 2; ++rt){
      int rbase = row0 + rt * 16 + lg * 4;
      f32x4 a4 = acc[rt][ct];
      #pragma unroll
      for (int r = 0; r < 4; ++r){
        int row = rbase + r;
        if (row < N){
          float t = a4[r] + bv;
          if (RELU) t = fmaxf(t, 0.f);
          ((ushort*)Cout)[(size_t)row * 128 + col] = f2bf(t);
        }
      }
    }
  }
}

// ---------------- GAT: 16 lanes per node, 3-deep gather pipeline, single-exp softmax ----------------
__global__ __launch_bounds__(256) void k_gat(uint* __restrict__ Hh,
                      const uint* __restrict__ HWh, const uint* __restrict__ HAh,
                      const int* __restrict__ off, const int* __restrict__ srcs,
                      const float* __restrict__ GW, const float* __restrict__ GB){
  int tid = threadIdx.x;
  int sub = tid & 15;
  int n = blockIdx.x * 16 + (tid >> 4);
  if (n >= NN) return;
  uint4 au = *(const uint4*)(HAh + (size_t)n * 64 + sub * 4);
  float a[8]; decode8(au, a);
  int e0 = off[n], deg = off[n + 1] - e0;
  float m = -INFINITY, den = 0.f;
  float acc[8] = {};
  uint4 w0v = {}, w1v = {}, w2v = {};
  if (deg > 0) w0v = *(const uint4*)(HWh + (size_t)srcs[e0] * 64 + sub * 4);
  if (deg > 1) w1v = *(const uint4*)(HWh + (size_t)srcs[e0 + 1] * 64 + sub * 4);
  if (deg > 2) w2v = *(const uint4*)(HWh + (size_t)srcs[e0 + 2] * 64 + sub * 4);
  for (int t = 0; t < deg; ++t){
    uint4 wn = {};
    if (t + 3 < deg) wn = *(const uint4*)(HWh + (size_t)srcs[e0 + t + 3] * 64 + sub * 4);
    float w[8]; decode8(w0v, w);
    float p = a[0]*w[0] + a[1]*w[1] + a[2]*w[2] + a[3]*w[3]
            + a[4]*w[4] + a[5]*w[5] + a[6]*w[6] + a[7]*w[7];
    #pragma unroll
    for (int o = 8; o; o >>= 1) p += __shfl_xor(p, o, 64);
    float d = p - m;
    float eB = __expf(-fabsf(d));       // exp(-|p-m|); first edge: exp(-inf)=0
    bool up = d > 0.f;
    float cf = up ? eB : 1.f;
    float ex = up ? 1.f : eB;
    den = den * cf + ex;
    #pragma unroll
    for (int q = 0; q < 8; ++q) acc[q] = acc[q] * cf + ex * w[q];
    if (up) m = p;
    w0v = w1v; w1v = w2v; w2v = wn;
  }
  float inv = 1.f / (den + 1e-16f);
  float hp[8];
  #pragma unroll
  for (int q = 0; q < 8; ++q) hp[q] = fmaxf(acc[q] * inv, 0.f);
  uint4 xu = *(const uint4*)(Hh + (size_t)n * 64 + sub * 4);
  float x[8]; decode8(xu, x);
  float gx[8], gh[8];
  *(float4*)&gx[0] = *(const float4*)(GW + sub * 8);
  *(float4*)&gx[4] = *(const float4*)(GW + sub * 8 + 4);
  *(float4*)&gh[0] = *(const float4*)(GW + 128 + sub * 8);
  *(float4*)&gh[4] = *(const float4*)(GW + 128 + sub * 8 + 4);
  float g = 0.f;
  #pragma unroll
  for (int q = 0; q < 8; ++q) g += x[q] * gx[q] + hp[q] * gh[q];
  #pragma unroll
  for (int o = 8; o; o >>= 1) g += __shfl_xor(g, o, 64);
  g += GB[0];
  float z = 1.f / (1.f + __expf(-g));
  #pragma unroll
  for (int q = 0; q < 8; ++q) x[q] = z * x[q] + (1.f - z) * hp[q];
  uint4 hw;
  hw.x = f2bf2(x[0], x[1]); hw.y = f2bf2(x[2], x[3]);
  hw.z = f2bf2(x[4], x[5]); hw.w = f2bf2(x[6], x[7]);
  *(uint4*)(Hh + (size_t)n * 64 + sub * 4) = hw;
}

// ---------------- interaction: 16 lanes per node, 3-deep pipeline ----------------
__global__ __launch_bounds__(256) void k_inter(uint* __restrict__ Hh,
                        const uint* __restrict__ Th,
                        const int* __restrict__ off, const int* __restrict__ srcs,
                        const float* __restrict__ GW, const float* __restrict__ GB){
  int tid = threadIdx.x;
  int sub = tid & 15;
  int n = blockIdx.x * 16 + (tid >> 4);
  if (n >= NN) return;
  int e0 = off[n], deg = off[n + 1] - e0;
  float acc[8] = {};
  uint4 w0v = {}, w1v = {}, w2v = {};
  if (deg > 0) w0v = *(const uint4*)(Th + (size_t)srcs[e0] * 64 + sub * 4);
  if (deg > 1) w1v = *(const uint4*)(Th + (size_t)srcs[e0 + 1] * 64 + sub * 4);
  if (deg > 2) w2v = *(const uint4*)(Th + (size_t)srcs[e0 + 2] * 64 + sub * 4);
  for (int t = 0; t < deg; ++t){
    uint4 wn = {};
    if (t + 3 < deg) wn = *(const uint4*)(Th + (size_t)srcs[e0 + t + 3] * 64 + sub * 4);
    float w[8]; decode8(w0v, w);
    #pragma unroll
    for (int q = 0; q < 8; ++q) acc[q] += w[q];
    w0v = w1v; w1v = w2v; w2v = wn;
  }
  uint4 xu = *(const uint4*)(Hh + (size_t)n * 64 + sub * 4);
  float x[8]; decode8(xu, x);
  float gx[8], gh[8];
  *(float4*)&gx[0] = *(const float4*)(GW + sub * 8);
  *(float4*)&gx[4] = *(const float4*)(GW + sub * 8 + 4);
  *(float4*)&gh[0] = *(const float4*)(GW + 128 + sub * 8);
  *(float4*)&gh[4] = *(const float4*)(GW + 128 + sub * 8 + 4);
  float g = 0.f;
  #pragma unroll
  for (int q = 0; q < 8; ++q) g += x[q] * gx[q] + acc[q] * gh[q];
  #pragma unroll
  for (int o = 8; o; o >>= 1) g += __shfl_xor(g, o, 64);
  g += GB[0];
  float z = 1.f / (1.f + __expf(-g));
  #pragma unroll
  for (int q = 0; q < 8; ++q) x[q] = z * x[q] + (1.f - z) * acc[q];
  uint4 hw;
  hw.x = f2bf2(x[0], x[1]); hw.y = f2bf2(x[2], x[3]);
  hw.z = f2bf2(x[4], x[5]); hw.w = f2bf2(x[6], x[7]);
  *(uint4*)(Hh + (size_t)n * 64 + sub * 4) = hw;
}

// ---------------- inter-graph edges: balanced chunks of i-sorted edge list ----------------
__global__ __launch_bounds__(256) void k_edges(
    const int* __restrict__ iI, const ull* __restrict__ jeI,
    const float4* __restrict__ PRAD, const uint* __restrict__ MB,
    const uint* __restrict__ Pd, const uint* __restrict__ Qd,
    const uint* __restrict__ Pe, const uint* __restrict__ Qe,
    const float* __restrict__ w2d, const float* __restrict__ b2d,
    const float* __restrict__ w2e, const float* __restrict__ b2e,
    const float* __restrict__ hbc, const float* __restrict__ hpc,
    float* __restrict__ geng, float* __restrict__ outdv){
  int tid = threadIdx.x;
  int sub = tid & 15;
  int gid = blockIdx.x * 16 + (tid >> 4);
  int ngrp = gridDim.x * 16;
  int e0 = (int)((long)EIN * gid / ngrp);
  int e1 = (int)((long)EIN * (gid + 1) / ngrp);
  if (e0 >= e1) return;
  float wdv[8], wev[8];
  *(float4*)&wdv[0] = *(const float4*)(w2d + sub * 8);
  *(float4*)&wdv[4] = *(const float4*)(w2d + sub * 8 + 4);
  *(float4*)&wev[0] = *(const float4*)(w2e + sub * 8);
  *(float4*)&wev[4] = *(const float4*)(w2e + sub * 8 + 4);
  float bd = b2d[0], be = b2e[0];
  float minhb = -hbc[0] * hbc[0], minhp = -hpc[0] * hpc[0];
  float E0 = 0.f, E1 = 0.f, E2 = 0.f, E3 = 0.f;
  int gcur = -1;
  float* part = geng + (size_t)(blockIdx.x & 7) * (NG * 4);

  // prime pipeline: edge e0
  int ia = iI[e0];
  ull je = jeI[e0];
  int ja = (int)(uint)je;
  uint4 pd0 = *(const uint4*)(Pd + (size_t)ia * 64 + sub * 4);
  uint4 pe0 = *(const uint4*)(Pe + (size_t)ia * 64 + sub * 4);
  uint4 qd0 = *(const uint4*)(Qd + (size_t)ja * 64 + sub * 4);
  uint4 qe0 = *(const uint4*)(Qe + (size_t)ja * 64 + sub * 4);
  float4 pri = PRAD[ia], prj = PRAD[ja];
  uint mbi = MB[ia], mbj = MB[ja];

  for (int e = e0; e < e1; ++e){
    // prefetch e+1
    ull jeN = 0; uint4 pdN = {}, peN = {}, qdN = {}, qeN = {};
    float4 priN = {}, prjN = {}; uint mbiN = 0, mbjN = 0;
    if (e + 1 < e1){
      int iN = iI[e + 1];
      jeN = jeI[e + 1];
      int jN = (int)(uint)jeN;
      pdN = *(const uint4*)(Pd + (size_t)iN * 64 + sub * 4);   // L1-hot (i-sorted)
      peN = *(const uint4*)(Pe + (size_t)iN * 64 + sub * 4);
      qdN = *(const uint4*)(Qd + (size_t)jN * 64 + sub * 4);
      qeN = *(const uint4*)(Qe + (size_t)jN * 64 + sub * 4);
      priN = PRAD[iN]; prjN = PRAD[jN]; mbiN = MB[iN]; mbjN = MB[jN];
    }
    float pdf[8], qdf[8], pef[8], qef[8];
    decode8(pd0, pdf); decode8(qd0, qdf); decode8(pe0, pef); decode8(qe0, qef);
    float sd = 0.f, se = 0.f;
    #pragma unroll
    for (int q = 0; q < 8; ++q){
      sd += fmaxf(pdf[q] + qdf[q], 0.f) * wdv[q];
      se += fmaxf(pef[q] + qef[q], 0.f) * wev[q];
    }
    #pragma unroll
    for (int o = 8; o; o >>= 1){
      sd += __shfl_xor(sd, o, 64);
      se += __shfl_xor(se, o, 64);
    }
    sd += bd; se += be;
    float dx = pri.x - prj.x, dy = pri.y - prj.y, dz = pri.z - prj.z;
    float D = sqrtf(dx * dx + dy * dy + dz * dz + 1e-10f);
    float rmask = (D >= 0.5f && D <= 5.0f) ? 1.f : 0.f;
    float ex2 = __expf(2.f * fminf(sd, 15.f));
    float th = __fdividef(ex2 - 1.f, ex2 + 1.f);
    float dvdw = th * DEV_VDW * rmask;
    float eps = __fdividef(1.f, 1.f + __expf(-se)) * (EPS_HI_ - EPS_LO_) + EPS_LO_;
    float R = pri.w + prj.w + dvdw;
    float dr = fmaxf(__fdividef(D, R), 0.5f);
    float nn2 = (dr < 1.f) ? 10.f : 6.f;
    float tp = __expf(-nn2 * __logf(dr));
    float ev = eps * (tp * tp - 2.f * tp);
    float dmr = D - R;
    float f1 = fminf(fmaxf(dmr * (-1.f / 0.7f), 0.f), 1.f);
    float f3 = fminf(fmaxf(1.5f - dmr, 0.f), 1.f);
    bool metI = mbi & 1, metJ = mbj & 1;
    bool donI = mbi & 2, donJ = mbj & 2;
    bool accI = mbi & 4, accJ = mbj & 4;
    bool hyI  = mbi & 8, hyJ  = mbj & 8;
    bool nm = !(metI || metJ);
    if (sub == 0) __builtin_nontemporal_store(dvdw, &outdv[(int)(je >> 32)]);
    int g = (int)(mbi >> 8);
    if (g != gcur){
      if (sub == 0 && gcur >= 0){
        atomicAdd(&part[gcur * 4 + 0], E0);
        atomicAdd(&part[gcur * 4 + 1], E1);
        atomicAdd(&part[gcur * 4 + 2], E2);
        atomicAdd(&part[gcur * 4 + 3], E3);
      }
      E0 = E1 = E2 = E3 = 0.f;
      gcur = g;
    }
    E0 += nm ? ev * rmask : 0.f;
    E1 += (((donI && accJ) || (accI && donJ)) && nm) ? minhb * f1 * rmask : 0.f;
    E2 += ((metI && accJ) || (accI && metJ)) ? minhb * f1 * rmask : 0.f;
    E3 += (hyI && hyJ && nm) ? minhp * f3 * rmask : 0.f;
    je = jeN; pd0 = pdN; pe0 = peN; qd0 = qdN; qe0 = qeN;
    pri = priN; prj = prjN; mbi = mbiN; mbj = mbjN;
  }
  if (sub == 0 && gcur >= 0){
    atomicAdd(&part[gcur * 4 + 0], E0);
    atomicAdd(&part[gcur * 4 + 1], E1);
    atomicAdd(&part[gcur * 4 + 2], E2);
    atomicAdd(&part[gcur * 4 + 3], E3);
  }
}

__global__ void k_final(const float* __restrict__ geng, const float* __restrict__ rotor,
                        const float* __restrict__ rc, float* __restrict__ out){
  int t = blockIdx.x * blockDim.x + threadIdx.x;
  if (t < NG * 4){
    int g = t >> 2;
    float s = 0.f;
    #pragma unroll
    for (int p = 0; p < 8; ++p) s += geng[p * NG * 4 + t];
    float pen = 1.f + rc[0] * rc[0] * rotor[g];
    out[t] = s / pen;
  }
}

extern "C" void kernel_launch(void* const* d_in, const int* in_sizes, int n_in,
                              void* d_out, int out_size, void* d_ws, size_t ws_size,
                              hipStream_t stream){
  (void)in_sizes; (void)n_in; (void)out_size; (void)ws_size;
  const float* X    = (const float*)d_in[0];
  const float* POS  = (const float*)d_in[1];
  const float* RAD  = (const float*)d_in[2];
  const float* ROT  = (const float*)d_in[3];
  const int* EIa    = (const int*)d_in[4];
  const int* EIc    = (const int*)d_in[5];
  const int* EIi    = (const int*)d_in[6];
  const int* BATCH  = (const int*)d_in[7];
  const int* Mmet = (const int*)d_in[8];
  const int* Mdon = (const int*)d_in[9];
  const int* Macc = (const int*)d_in[10];
  const int* Mhyd = (const int*)d_in[11];
  const float* embW  = (const float*)d_in[12];
  const float* gatW  = (const float*)d_in[13];
  const float* gatWb = (const float*)d_in[14];
  const float* gatA  = (const float*)d_in[15];
  const float* gatGw = (const float*)d_in[16];
  const float* gatGb = (const float*)d_in[17];
  const float* intW  = (const float*)d_in[18];
  const float* intWb = (const float*)d_in[19];
  const float* intGw = (const float*)d_in[20];
  const float* intGb = (const float*)d_in[21];
  const float* ew1 = (const float*)d_in[22];
  const float* eb1 = (const float*)d_in[23];
  const float* ew2 = (const float*)d_in[24];
  const float* eb2 = (const float*)d_in[25];
  const float* dw1 = (const float*)d_in[26];
  const float* db1 = (const float*)d_in[27];
  const float* dw2 = (const float*)d_in[28];
  const float* db2 = (const float*)d_in[29];
  const float* hbc = (const float*)d_in[30];
  const float* hpc = (const float*)d_in[31];
  const float* rcc = (const float*)d_in[32];
  float* out = (float*)d_out;

  char* w = (char*)d_ws;
  uint* Hh   = (uint*)w;  w += (size_t)NN * 64 * 4;    // 12.8 MB bf16 state
  uint* BAh  = (uint*)w;  w += (size_t)NN * 64 * 4;
  uint* BBh  = (uint*)w;  w += (size_t)NN * 64 * 4;
  uint* Peh  = (uint*)w;  w += (size_t)NN * 64 * 4;
  uint* Qeh  = (uint*)w;  w += (size_t)NN * 64 * 4;
  uint* WT   = (uint*)w;  w += (size_t)13 * 8192 * 4;
  float* BIASALL = (float*)w; w += (size_t)13 * 128 * 4;
  float4* PRAD = (float4*)w; w += (size_t)NN * 16;
  uint* MBb  = (uint*)w;  w += (size_t)NN * 4;
  // contiguous zero region: cntA, cntC, cntI, GENG
  int* cntA = (int*)w; w += (size_t)NN * 4;
  int* cntC = (int*)w; w += (size_t)NN * 4;
  int* cntI = (int*)w; w += (size_t)NN * 4;
  float* GENG = (float*)w; w += (size_t)8 * 512 * 4;
  size_t zero_bytes = (size_t)3 * NN * 4 + (size_t)8 * 512 * 4;
  int* offA = (int*)w; w += (size_t)(NN + 1) * 4;
  int* curA = (int*)w; w += (size_t)NN * 4;
  int* srcA = (int*)w; w += (size_t)EA * 4;
  int* offC = (int*)w; w += (size_t)(NN + 1) * 4;
  int* curC = (int*)w; w += (size_t)NN * 4;
  int* srcC = (int*)w; w += (size_t)EC * 4;
  int* offI = (int*)w; w += (size_t)(NN + 1) * 4;
  int* curI = (int*)w; w += (size_t)NN * 4;
  ull* jeI  = (ull*)w; w += (size_t)EIN * 8;
  int* iI   = (int*)w; w += (size_t)EIN * 4;
  uint* Th  = BAh;   // aliases: phases are sequential
  uint* Pdh = BAh;   // tail outputs: BAh,BBh,Peh,Qeh contiguous
  uint* Qdh = BBh;

  hipMemsetAsync(cntA, 0, zero_bytes, stream);

  k_count<<<2560, 256, 0, stream>>>(EIa + EA, EIc + EC, EIi, cntA, cntC, cntI);
  k_scan3<<<3, 1024, 0, stream>>>(cntA, offA, curA, cntC, offC, curC, cntI, offI, curI);
  k_place<<<2560, 256, 0, stream>>>(EIa, EIc, EIi, curA, srcA, curC, srcC, curI, jeI, iI);

  k_misc<<<2258, 256, 0, stream>>>(gatW, gatA, intW, dw1, ew1, gatWb, intWb, db1, eb1,
                                   WT, BIASALL, POS, RAD, Mmet, Mdon, Macc, Mhyd, BATCH,
                                   PRAD, MBb, X, embW, Hh);

  int gg = (NN + 127) / 128;
  int nodeGrid = (NN + 15) / 16;
  for (int l = 0; l < 3; ++l){
    // y=0: BAh = Hh@W + Wb ; y=1: BBh = Hh@(W@A) + Wb@A  (independent)
    k_gemm_mfma<false><<<dim3(gg, 2), 256, 0, stream>>>(Hh, WT + (size_t)l * 8192, (size_t)3 * 8192,
                                                        BIASALL + l * 128, (size_t)3 * 128,
                                                        BAh, (size_t)NN * 64, NN);
    k_gat<<<nodeGrid, 256, 0, stream>>>(Hh, BAh, BBh, offA, srcA, gatGw + l * 256, gatGb + l);
  }
  for (int l = 0; l < 3; ++l){
    k_gemm_mfma<true><<<dim3(gg, 1), 256, 0, stream>>>(Hh, WT + (size_t)(6 + l) * 8192, 0,
                                                       BIASALL + (6 + l) * 128, 0, Th, 0, NN);
    k_inter<<<nodeGrid, 256, 0, stream>>>(Hh, Th, offC, srcC, intGw + l * 256, intGb + l);
  }
  // tail: 4 GEMMs fused via blockIdx.y -> Pd,Qd,Pe,Qe
  k_gemm_mfma<false><<<dim3(gg, 4), 256, 0, stream>>>(Hh, WT + (size_t)9 * 8192, (size_t)8192,
                                                      BIASALL + 9 * 128, (size_t)128,
                                                      BAh, (size_t)NN * 64, NN);

  k_edges<<<nodeGrid, 256, 0, stream>>>(iI, jeI, PRAD, MBb, Pdh, Qdh, Peh, Qeh,
                                        dw2, db2, ew2, eb2, hbc, hpc,
                                        GENG, out + 512);
  k_final<<<2, 256, 0, stream>>>(GENG, ROT, rcc, out);
}

// Round 10
// 808.351 us; speedup vs baseline: 1.2577x; 1.2577x over previous
//
#include <hip/hip_runtime.h>
#include <math.h>

#define NN 50000
#define EA 800000
#define EC 400000
#define EIN 600000
#define NG 128
#define FIN 54

#define DEV_VDW 0.2f
#define EPS_LO_ 0.0178f
#define EPS_HI_ 0.2f

typedef unsigned int uint;
typedef unsigned short ushort;
typedef unsigned long long ull;
typedef __attribute__((ext_vector_type(8))) short bf16x8;
typedef __attribute__((ext_vector_type(4))) float f32x4;

__device__ __forceinline__ ushort f2bf(float f){
  uint x = __float_as_uint(f);
  uint r = x + 0x7fffu + ((x >> 16) & 1u);
  return (ushort)(r >> 16);
}
__device__ __forceinline__ uint f2bf2(float a, float b){
  return (uint)f2bf(a) | ((uint)f2bf(b) << 16);
}
__device__ __forceinline__ void decode8(uint4 u, float* f){
  f[0] = __uint_as_float(u.x << 16); f[1] = __uint_as_float(u.x & 0xffff0000u);
  f[2] = __uint_as_float(u.y << 16); f[3] = __uint_as_float(u.y & 0xffff0000u);
  f[4] = __uint_as_float(u.z << 16); f[5] = __uint_as_float(u.z & 0xffff0000u);
  f[6] = __uint_as_float(u.w << 16); f[7] = __uint_as_float(u.w & 0xffff0000u);
}

// ---------------- CSR rank (count with returned rank), A+C fused ----------------
__global__ void k_rank(const int* __restrict__ dstA, const int* __restrict__ dstC,
                       int* __restrict__ cntA, int* __restrict__ cntC,
                       int* __restrict__ rnkA, int* __restrict__ rnkC){
  int b = blockIdx.x;
  if (b < 1024){
    for (int i = b * 256 + threadIdx.x; i < EA; i += 1024 * 256)
      rnkA[i] = atomicAdd(&cntA[dstA[i]], 1);
  } else {
    int bid = b - 1024;
    for (int i = bid * 256 + threadIdx.x; i < EC; i += 512 * 256)
      rnkC[i] = atomicAdd(&cntC[dstC[i]], 1);
  }
}

__global__ void k_scan2(const int* __restrict__ cntA, int* __restrict__ offA,
                        const int* __restrict__ cntC, int* __restrict__ offC){
  const int* cnt = blockIdx.x ? cntC : cntA;
  int* off = blockIdx.x ? offC : offA;
  int n = NN;
  __shared__ int wsums[16];
  __shared__ int run_s;
  int tid = threadIdx.x;            // 1024
  int lane = tid & 63, w = tid >> 6;
  if (tid == 0) run_s = 0;
  __syncthreads();
  for (int base = 0; base < n; base += 1024){
    int run = run_s;
    int i = base + tid;
    int v = (i < n) ? cnt[i] : 0;
    int s = v;
    #pragma unroll
    for (int o = 1; o < 64; o <<= 1){ int t = __shfl_up(s, o, 64); if (lane >= o) s += t; }
    if (lane == 63) wsums[w] = s;
    __syncthreads();
    if (w == 0 && lane < 16){
      int t = wsums[lane];
      #pragma unroll
      for (int o = 1; o < 16; o <<= 1){ int u = __shfl_up(t, o, 64); if (lane >= o) t += u; }
      wsums[lane] = t;
    }
    __syncthreads();
    int woff = (w == 0) ? 0 : wsums[w - 1];
    int excl = run + woff + (s - v);
    if (i < n) off[i] = excl;
    int tot = wsums[15];
    __syncthreads();
    if (tid == 0) run_s = run + tot;
    __syncthreads();
  }
  if (threadIdx.x == 0) off[n] = run_s;
}

// ---------------- place: no atomics, nontemporal scattered stores ----------------
__global__ void k_place(const int* __restrict__ eiA, const int* __restrict__ eiC,
                        const int* __restrict__ offA, const int* __restrict__ rnkA, int* __restrict__ srcA,
                        const int* __restrict__ offC, const int* __restrict__ rnkC, int* __restrict__ srcC){
  int b = blockIdx.x;
  if (b < 1024){
    for (int i = b * 256 + threadIdx.x; i < EA; i += 1024 * 256){
      int d = eiA[EA + i];
      __builtin_nontemporal_store(eiA[i], &srcA[offA[d] + rnkA[i]]);
    }
  } else {
    int bid = b - 1024;
    for (int i = bid * 256 + threadIdx.x; i < EC; i += 512 * 256){
      int d = eiC[EC + i];
      __builtin_nontemporal_store(eiC[i], &srcC[offC[d] + rnkC[i]]);
    }
  }
}

// ---------------- node static info ----------------
__global__ void k_nodeinfo(const float* __restrict__ POS, const float* __restrict__ RAD,
                           const int* __restrict__ Mmet, const int* __restrict__ Mdon,
                           const int* __restrict__ Macc, const int* __restrict__ Mhyd,
                           const int* __restrict__ BATCH,
                           float4* __restrict__ PRAD, uint* __restrict__ MB){
  int n = blockIdx.x * 256 + threadIdx.x;
  if (n < NN){
    PRAD[n] = make_float4(POS[3*n], POS[3*n+1], POS[3*n+2], RAD[n]);
    uint m = (Mmet[n] ? 1u : 0u) | (Mdon[n] ? 2u : 0u) | (Macc[n] ? 4u : 0u) |
             (Mhyd[n] ? 8u : 0u) | ((uint)BATCH[n] << 8);
    MB[n] = m;
  }
}

// ---------------- weight prep ----------------
// WT slots ([n][k] bf16): 0-2 gatW, 3-5 WA=gatW@gatA, 6-8 intW, 9-10 dw1, 11-12 ew1
// BIASALL[13][128]: 0-2 gatWb, 3-5 gatWb@gatA, 6-8 intWb, 9 db1, 10 zero, 11 eb1, 12 zero
__global__ __launch_bounds__(256) void k_prepw(const float* __restrict__ gatW, const float* __restrict__ gatA,
                        const float* __restrict__ intW, const float* __restrict__ dw1,
                        const float* __restrict__ ew1,
                        const float* __restrict__ gatWb, const float* __restrict__ intWb,
                        const float* __restrict__ db1, const float* __restrict__ eb1,
                        uint* __restrict__ Wt, float* __restrict__ BIASALL){
  __shared__ ushort L[128 * 132];
  int m = blockIdx.x;
  int tid = threadIdx.x;
  if (m == 13){
    for (int idx = tid; idx < 13 * 128; idx += 256){
      int slot = idx >> 7, c = idx & 127;
      if (slot >= 3 && slot < 6) continue;   // written by WA blocks
      float v = 0.f;
      if (slot < 3) v = gatWb[slot * 128 + c];
      else if (slot < 9) v = intWb[(slot - 6) * 128 + c];
      else if (slot == 9) v = db1[c];
      else if (slot == 11) v = eb1[c];
      BIASALL[idx] = v;
    }
    return;
  }
  if (m >= 3 && m < 6){
    int l = m - 3;
    const float* Wf  = gatW + l * 16384;
    const float* Af  = gatA + l * 16384;
    const float* Wbf = gatWb + l * 128;
    for (int idx = tid; idx < 16384; idx += 256){
      int k = idx >> 7, n = idx & 127;
      L[k * 132 + n] = f2bf(Af[idx]);
    }
    __syncthreads();
    int r = tid >> 1, ch = tid & 1;
    float accv[64];
    #pragma unroll
    for (int c = 0; c < 64; ++c) accv[c] = 0.f;
    float accb = 0.f;
    int bc = tid & 127;
    for (int mm = 0; mm < 128; ++mm){
      float wv = Wf[r * 128 + mm];
      const uint* Lr32 = (const uint*)&L[mm * 132 + ch * 64];
      #pragma unroll
      for (int c2 = 0; c2 < 32; ++c2){
        uint u = Lr32[c2];
        accv[2 * c2]     += wv * __uint_as_float(u << 16);
        accv[2 * c2 + 1] += wv * __uint_as_float(u & 0xffff0000u);
      }
      accb += Wbf[mm] * __uint_as_float((uint)L[mm * 132 + bc] << 16);
    }
    __syncthreads();
    #pragma unroll
    for (int c = 0; c < 64; ++c) L[r * 132 + ch * 64 + c] = f2bf(accv[c]);
    if (tid < 128) BIASALL[(3 + l) * 128 + tid] = accb;
    __syncthreads();
    int n = tid & 127, half = tid >> 7;
    uint* outp = Wt + (size_t)m * 8192 + n * 64 + half * 32;
    #pragma unroll
    for (int kk2 = 0; kk2 < 32; ++kk2){
      int k = half * 64 + 2 * kk2;
      uint u = (uint)L[k * 132 + n] | ((uint)L[(k + 1) * 132 + n] << 16);
      outp[kk2] = u;
    }
    return;
  }
  const float* src = (m < 3)  ? gatW + m * 16384 :
                     (m < 9)  ? intW + (m - 6) * 16384 :
                     (m < 11) ? dw1 + (m - 9) * 16384 :
                                ew1 + (m - 11) * 16384;
  for (int idx = tid; idx < 16384; idx += 256){
    int k = idx >> 7, n = idx & 127;
    L[k * 132 + n] = f2bf(src[idx]);
  }
  __syncthreads();
  int n = tid & 127, half = tid >> 7;
  uint* outp = Wt + (size_t)m * 8192 + n * 64 + half * 32;
  #pragma unroll
  for (int kk2 = 0; kk2 < 32; ++kk2){
    int k = half * 64 + 2 * kk2;
    uint u = (uint)L[k * 132 + n] | ((uint)L[(k + 1) * 132 + n] << 16);
    outp[kk2] = u;
  }
}

// ---------------- embed: Hh = bf16(X @ W) ----------------
__global__ void k_embed(const float* __restrict__ X, const float* __restrict__ W,
                        uint* __restrict__ Hh){
  __shared__ float Wls[FIN * 128];
  int tid = threadIdx.x; // 128
  for (int i = tid; i < FIN * 128; i += 128) Wls[i] = W[i];
  __syncthreads();
  for (int row = blockIdx.x; row < NN; row += gridDim.x){
    const float* xr = X + row * FIN;
    float acc = 0.f;
    #pragma unroll
    for (int k = 0; k < FIN; ++k) acc += xr[k] * Wls[k * 128 + tid];
    ((ushort*)Hh)[(size_t)row * 128 + tid] = f2bf(acc);
  }
}

// ---------------- MFMA GEMM with y-indexed (B, bias, C) sets ----------------
template<bool RELU>
__global__ __launch_bounds__(256) void k_gemm_mfma(const uint* __restrict__ Ah,
        const uint* __restrict__ Bt0, size_t strideB,
        const float* __restrict__ bias0, size_t strideBias,
        uint* __restrict__ C0, size_t strideC, int N){
  const uint* Bt = Bt0 + (size_t)blockIdx.y * strideB;
  const float* bias = bias0 + (size_t)blockIdx.y * strideBias;
  uint* Cout = C0 + (size_t)blockIdx.y * strideC;
  int tid = threadIdx.x;
  int lane = tid & 63;
  int wv = tid >> 6;                      // 0..3
  int row0 = blockIdx.x * 128 + wv * 32;
  int l15 = lane & 15, lg = lane >> 4;
  int ra0 = row0 + l15, ra1 = row0 + 16 + l15;
  const uint* pa0 = Ah + (size_t)(ra0 < N ? ra0 : 0) * 64 + lg * 4;
  const uint* pa1 = Ah + (size_t)(ra1 < N ? ra1 : 0) * 64 + lg * 4;
  const uint* pb  = Bt + (size_t)l15 * 64 + lg * 4;
  f32x4 acc[2][8] = {};
  #pragma unroll
  for (int c = 0; c < 4; ++c){
    bf16x8 a0 = *(const bf16x8*)(pa0 + c * 16);
    bf16x8 a1 = *(const bf16x8*)(pa1 + c * 16);
    #pragma unroll
    for (int ct = 0; ct < 8; ++ct){
      bf16x8 b = *(const bf16x8*)(pb + ct * 1024 + c * 16);
      acc[0][ct] = __builtin_amdgcn_mfma_f32_16x16x32_bf16(a0, b, acc[0][ct], 0, 0, 0);
      acc[1][ct] = __builtin_amdgcn_mfma_f32_16x16x32_bf16(a1, b, acc[1][ct], 0, 0, 0);
    }
  }
  #pragma unroll
  for (int ct = 0; ct < 8; ++ct){
    int col = ct * 16 + l15;
    float bv = bias[col];
    #pragma unroll
    for (int rt = 0; rt < 2; ++rt){
      int rbase = row0 + rt * 16 + lg * 4;
      f32x4 a4 = acc[rt][ct];
      #pragma unroll
      for (int r = 0; r < 4; ++r){
        int row = rbase + r;
        if (row < N){
          float t = a4[r] + bv;
          if (RELU) t = fmaxf(t, 0.f);
          ((ushort*)Cout)[(size_t)row * 128 + col] = f2bf(t);
        }
      }
    }
  }
}

// ---------------- GAT: 16 lanes per node, 3-deep gather pipeline ----------------
__global__ __launch_bounds__(256) void k_gat(uint* __restrict__ Hh,
                      const uint* __restrict__ HWh, const uint* __restrict__ HAh,
                      const int* __restrict__ off, const int* __restrict__ srcs,
                      const float* __restrict__ GW, const float* __restrict__ GB){
  int tid = threadIdx.x;
  int sub = tid & 15;
  int n = blockIdx.x * 16 + (tid >> 4);
  if (n >= NN) return;
  uint4 au = *(const uint4*)(HAh + (size_t)n * 64 + sub * 4);
  float a[8]; decode8(au, a);
  int e0 = off[n], deg = off[n + 1] - e0;
  float m = -INFINITY, den = 0.f;
  float acc[8] = {};
  uint4 w0v = {}, w1v = {}, w2v = {};
  if (deg > 0) w0v = *(const uint4*)(HWh + (size_t)srcs[e0] * 64 + sub * 4);
  if (deg > 1) w1v = *(const uint4*)(HWh + (size_t)srcs[e0 + 1] * 64 + sub * 4);
  if (deg > 2) w2v = *(const uint4*)(HWh + (size_t)srcs[e0 + 2] * 64 + sub * 4);
  for (int t = 0; t < deg; ++t){
    uint4 wn = {};
    if (t + 3 < deg) wn = *(const uint4*)(HWh + (size_t)srcs[e0 + t + 3] * 64 + sub * 4);
    float w[8]; decode8(w0v, w);
    float p = a[0]*w[0] + a[1]*w[1] + a[2]*w[2] + a[3]*w[3]
            + a[4]*w[4] + a[5]*w[5] + a[6]*w[6] + a[7]*w[7];
    #pragma unroll
    for (int o = 8; o; o >>= 1) p += __shfl_xor(p, o, 64);
    float mn = fmaxf(m, p);
    float cf = __expf(m - mn);   // exp(-inf)=0 on first edge
    float ex = __expf(p - mn);
    den = den * cf + ex;
    #pragma unroll
    for (int q = 0; q < 8; ++q) acc[q] = acc[q] * cf + ex * w[q];
    m = mn;
    w0v = w1v; w1v = w2v; w2v = wn;
  }
  float inv = 1.f / (den + 1e-16f);
  float hp[8];
  #pragma unroll
  for (int q = 0; q < 8; ++q) hp[q] = fmaxf(acc[q] * inv, 0.f);
  uint4 xu = *(const uint4*)(Hh + (size_t)n * 64 + sub * 4);
  float x[8]; decode8(xu, x);
  float gx[8], gh[8];
  *(float4*)&gx[0] = *(const float4*)(GW + sub * 8);
  *(float4*)&gx[4] = *(const float4*)(GW + sub * 8 + 4);
  *(float4*)&gh[0] = *(const float4*)(GW + 128 + sub * 8);
  *(float4*)&gh[4] = *(const float4*)(GW + 128 + sub * 8 + 4);
  float g = 0.f;
  #pragma unroll
  for (int q = 0; q < 8; ++q) g += x[q] * gx[q] + hp[q] * gh[q];
  #pragma unroll
  for (int o = 8; o; o >>= 1) g += __shfl_xor(g, o, 64);
  g += GB[0];
  float z = 1.f / (1.f + __expf(-g));
  #pragma unroll
  for (int q = 0; q < 8; ++q) x[q] = z * x[q] + (1.f - z) * hp[q];
  uint4 hw;
  hw.x = f2bf2(x[0], x[1]); hw.y = f2bf2(x[2], x[3]);
  hw.z = f2bf2(x[4], x[5]); hw.w = f2bf2(x[6], x[7]);
  *(uint4*)(Hh + (size_t)n * 64 + sub * 4) = hw;
}

// ---------------- interaction: 16 lanes per node, 3-deep pipeline ----------------
__global__ __launch_bounds__(256) void k_inter(uint* __restrict__ Hh,
                        const uint* __restrict__ Th,
                        const int* __restrict__ off, const int* __restrict__ srcs,
                        const float* __restrict__ GW, const float* __restrict__ GB){
  int tid = threadIdx.x;
  int sub = tid & 15;
  int n = blockIdx.x * 16 + (tid >> 4);
  if (n >= NN) return;
  int e0 = off[n], deg = off[n + 1] - e0;
  float acc[8] = {};
  uint4 w0v = {}, w1v = {}, w2v = {};
  if (deg > 0) w0v = *(const uint4*)(Th + (size_t)srcs[e0] * 64 + sub * 4);
  if (deg > 1) w1v = *(const uint4*)(Th + (size_t)srcs[e0 + 1] * 64 + sub * 4);
  if (deg > 2) w2v = *(const uint4*)(Th + (size_t)srcs[e0 + 2] * 64 + sub * 4);
  for (int t = 0; t < deg; ++t){
    uint4 wn = {};
    if (t + 3 < deg) wn = *(const uint4*)(Th + (size_t)srcs[e0 + t + 3] * 64 + sub * 4);
    float w[8]; decode8(w0v, w);
    #pragma unroll
    for (int q = 0; q < 8; ++q) acc[q] += w[q];
    w0v = w1v; w1v = w2v; w2v = wn;
  }
  uint4 xu = *(const uint4*)(Hh + (size_t)n * 64 + sub * 4);
  float x[8]; decode8(xu, x);
  float gx[8], gh[8];
  *(float4*)&gx[0] = *(const float4*)(GW + sub * 8);
  *(float4*)&gx[4] = *(const float4*)(GW + sub * 8 + 4);
  *(float4*)&gh[0] = *(const float4*)(GW + 128 + sub * 8);
  *(float4*)&gh[4] = *(const float4*)(GW + 128 + sub * 8 + 4);
  float g = 0.f;
  #pragma unroll
  for (int q = 0; q < 8; ++q) g += x[q] * gx[q] + acc[q] * gh[q];
  #pragma unroll
  for (int o = 8; o; o >>= 1) g += __shfl_xor(g, o, 64);
  g += GB[0];
  float z = 1.f / (1.f + __expf(-g));
  #pragma unroll
  for (int q = 0; q < 8; ++q) x[q] = z * x[q] + (1.f - z) * acc[q];
  uint4 hw;
  hw.x = f2bf2(x[0], x[1]); hw.y = f2bf2(x[2], x[3]);
  hw.z = f2bf2(x[4], x[5]); hw.w = f2bf2(x[6], x[7]);
  *(uint4*)(Hh + (size_t)n * 64 + sub * 4) = hw;
}

// ---------------- final inter-graph edges: 16 lanes per edge, strided, 1-deep pipeline ----------------
__global__ __launch_bounds__(256) void k_edges(
    const int* __restrict__ EI,
    const float4* __restrict__ PRAD, const uint* __restrict__ MB,
    const uint* __restrict__ Pd, const uint* __restrict__ Qd,
    const uint* __restrict__ Pe, const uint* __restrict__ Qe,
    const float* __restrict__ w2d, const float* __restrict__ b2d,
    const float* __restrict__ w2e, const float* __restrict__ b2e,
    const float* __restrict__ hbc, const float* __restrict__ hpc,
    float* __restrict__ geng, float* __restrict__ outdv){
  __shared__ float eg[NG * 4];
  int tid = threadIdx.x;
  for (int i = tid; i < NG * 4; i += 256) eg[i] = 0.f;
  __syncthreads();
  int sub = tid & 15;
  int gid = blockIdx.x * 16 + (tid >> 4);
  int ngrp = gridDim.x * 16;
  float wdv[8], wev[8];
  *(float4*)&wdv[0] = *(const float4*)(w2d + sub * 8);
  *(float4*)&wdv[4] = *(const float4*)(w2d + sub * 8 + 4);
  *(float4*)&wev[0] = *(const float4*)(w2e + sub * 8);
  *(float4*)&wev[4] = *(const float4*)(w2e + sub * 8 + 4);
  float bd = b2d[0], be = b2e[0];
  float minhb = -hbc[0] * hbc[0], minhp = -hpc[0] * hpc[0];

  int e = gid;
  uint4 pd0 = {}, qd0 = {}, pe0 = {}, qe0 = {};
  float4 pri0 = {}, prj0 = {};
  uint mbi0 = 0, mbj0 = 0;
  int i1 = 0, j1 = 0;
  if (e < EIN){
    int i0 = EI[e], j0 = EI[EIN + e];
    pd0 = *(const uint4*)(Pd + (size_t)i0 * 64 + sub * 4);
    qd0 = *(const uint4*)(Qd + (size_t)j0 * 64 + sub * 4);
    pe0 = *(const uint4*)(Pe + (size_t)i0 * 64 + sub * 4);
    qe0 = *(const uint4*)(Qe + (size_t)j0 * 64 + sub * 4);
    pri0 = PRAD[i0]; prj0 = PRAD[j0]; mbi0 = MB[i0]; mbj0 = MB[j0];
  }
  if (e + ngrp < EIN){ i1 = EI[e + ngrp]; j1 = EI[EIN + e + ngrp]; }

  for (; e < EIN; e += ngrp){
    uint4 pd1 = {}, qd1 = {}, pe1 = {}, qe1 = {};
    float4 pri1 = {}, prj1 = {};
    uint mbi1 = 0, mbj1 = 0;
    int i2 = 0, j2 = 0;
    if (e + ngrp < EIN){
      pd1 = *(const uint4*)(Pd + (size_t)i1 * 64 + sub * 4);
      qd1 = *(const uint4*)(Qd + (size_t)j1 * 64 + sub * 4);
      pe1 = *(const uint4*)(Pe + (size_t)i1 * 64 + sub * 4);
      qe1 = *(const uint4*)(Qe + (size_t)j1 * 64 + sub * 4);
      pri1 = PRAD[i1]; prj1 = PRAD[j1]; mbi1 = MB[i1]; mbj1 = MB[j1];
    }
    if (e + 2 * ngrp < EIN){ i2 = EI[e + 2 * ngrp]; j2 = EI[EIN + e + 2 * ngrp]; }

    float pdf[8], qdf[8], pef[8], qef[8];
    decode8(pd0, pdf); decode8(qd0, qdf); decode8(pe0, pef); decode8(qe0, qef);
    float sd = 0.f, se = 0.f;
    #pragma unroll
    for (int q = 0; q < 8; ++q){
      sd += fmaxf(pdf[q] + qdf[q], 0.f) * wdv[q];
      se += fmaxf(pef[q] + qef[q], 0.f) * wev[q];
    }
    #pragma unroll
    for (int o = 8; o; o >>= 1){
      sd += __shfl_xor(sd, o, 64);
      se += __shfl_xor(se, o, 64);
    }
    sd += bd; se += be;
    float dx = pri0.x - prj0.x, dy = pri0.y - prj0.y, dz = pri0.z - prj0.z;
    float D = sqrtf(dx * dx + dy * dy + dz * dz + 1e-10f);
    float rmask = (D >= 0.5f && D <= 5.0f) ? 1.f : 0.f;
    float ex2 = __expf(2.f * fminf(sd, 15.f));
    float th = __fdividef(ex2 - 1.f, ex2 + 1.f);
    float dvdw = th * DEV_VDW * rmask;
    float eps = __fdividef(1.f, 1.f + __expf(-se)) * (EPS_HI_ - EPS_LO_) + EPS_LO_;
    float R = pri0.w + prj0.w + dvdw;
    float dr = fmaxf(__fdividef(D, R), 0.5f);
    float nn2 = (dr < 1.f) ? 10.f : 6.f;
    float tp = __expf(-nn2 * __logf(dr));
    float ev = eps * (tp * tp - 2.f * tp);
    float dmr = D - R;
    float f1 = fminf(fmaxf(dmr * (-1.f / 0.7f), 0.f), 1.f);
    float f3 = fminf(fmaxf(1.5f - dmr, 0.f), 1.f);
    bool metI = mbi0 & 1, metJ = mbj0 & 1;
    bool donI = mbi0 & 2, donJ = mbj0 & 2;
    bool accI = mbi0 & 4, accJ = mbj0 & 4;
    bool hyI  = mbi0 & 8, hyJ  = mbj0 & 8;
    bool nm = !(metI || metJ);
    float E0 = nm ? ev * rmask : 0.f;
    float E1 = (((donI && accJ) || (accI && donJ)) && nm) ? minhb * f1 * rmask : 0.f;
    float E2 = ((metI && accJ) || (accI && metJ)) ? minhb * f1 * rmask : 0.f;
    float E3 = (hyI && hyJ && nm) ? minhp * f3 * rmask : 0.f;
    if (sub == 0){
      outdv[e] = dvdw;
      int g = (int)(mbi0 >> 8) * 4;
      atomicAdd(&eg[g + 0], E0);
      atomicAdd(&eg[g + 1], E1);
      atomicAdd(&eg[g + 2], E2);
      atomicAdd(&eg[g + 3], E3);
    }
    pd0 = pd1; qd0 = qd1; pe0 = pe1; qe0 = qe1;
    pri0 = pri1; prj0 = prj1; mbi0 = mbi1; mbj0 = mbj1;
    i1 = i2; j1 = j2;
  }
  __syncthreads();
  float* part = geng + (size_t)(blockIdx.x & 7) * (NG * 4);
  for (int i2 = tid; i2 < NG * 4; i2 += 256) atomicAdd(&part[i2], eg[i2]);
}

__global__ void k_final(const float* __restrict__ geng, const float* __restrict__ rotor,
                        const float* __restrict__ rc, float* __restrict__ out){
  int t = blockIdx.x * blockDim.x + threadIdx.x;
  if (t < NG * 4){
    int g = t >> 2;
    float s = 0.f;
    #pragma unroll
    for (int p = 0; p < 8; ++p) s += geng[p * NG * 4 + t];
    float pen = 1.f + rc[0] * rc[0] * rotor[g];
    out[t] = s / pen;
  }
}

extern "C" void kernel_launch(void* const* d_in, const int* in_sizes, int n_in,
                              void* d_out, int out_size, void* d_ws, size_t ws_size,
                              hipStream_t stream){
  (void)in_sizes; (void)n_in; (void)out_size; (void)ws_size;
  const float* X    = (const float*)d_in[0];
  const float* POS  = (const float*)d_in[1];
  const float* RAD  = (const float*)d_in[2];
  const float* ROT  = (const float*)d_in[3];
  const int* EIa    = (const int*)d_in[4];
  const int* EIc    = (const int*)d_in[5];
  const int* EIi    = (const int*)d_in[6];
  const int* BATCH  = (const int*)d_in[7];
  const int* Mmet = (const int*)d_in[8];
  const int* Mdon = (const int*)d_in[9];
  const int* Macc = (const int*)d_in[10];
  const int* Mhyd = (const int*)d_in[11];
  const float* embW  = (const float*)d_in[12];
  const float* gatW  = (const float*)d_in[13];
  const float* gatWb = (const float*)d_in[14];
  const float* gatA  = (const float*)d_in[15];
  const float* gatGw = (const float*)d_in[16];
  const float* gatGb = (const float*)d_in[17];
  const float* intW  = (const float*)d_in[18];
  const float* intWb = (const float*)d_in[19];
  const float* intGw = (const float*)d_in[20];
  const float* intGb = (const float*)d_in[21];
  const float* ew1 = (const float*)d_in[22];
  const float* eb1 = (const float*)d_in[23];
  const float* ew2 = (const float*)d_in[24];
  const float* eb2 = (const float*)d_in[25];
  const float* dw1 = (const float*)d_in[26];
  const float* db1 = (const float*)d_in[27];
  const float* dw2 = (const float*)d_in[28];
  const float* db2 = (const float*)d_in[29];
  const float* hbc = (const float*)d_in[30];
  const float* hpc = (const float*)d_in[31];
  const float* rcc = (const float*)d_in[32];
  float* out = (float*)d_out;

  char* w = (char*)d_ws;
  uint* Hh   = (uint*)w;  w += (size_t)NN * 64 * 4;    // 12.8 MB bf16 state
  uint* BAh  = (uint*)w;  w += (size_t)NN * 64 * 4;
  uint* BBh  = (uint*)w;  w += (size_t)NN * 64 * 4;
  uint* Peh  = (uint*)w;  w += (size_t)NN * 64 * 4;
  uint* Qeh  = (uint*)w;  w += (size_t)NN * 64 * 4;
  uint* WT   = (uint*)w;  w += (size_t)13 * 8192 * 4;
  float* BIASALL = (float*)w; w += (size_t)13 * 128 * 4;
  float4* PRAD = (float4*)w; w += (size_t)NN * 16;
  uint* MBb  = (uint*)w;  w += (size_t)NN * 4;
  // contiguous zero region: cntA, cntC, GENG
  int* cntA = (int*)w; w += (size_t)NN * 4;
  int* cntC = (int*)w; w += (size_t)NN * 4;
  float* GENG = (float*)w; w += (size_t)8 * 512 * 4;
  size_t zero_bytes = (size_t)2 * NN * 4 + (size_t)8 * 512 * 4;
  int* offA = (int*)w; w += (size_t)(NN + 1) * 4;
  int* srcA = (int*)w; w += (size_t)EA * 4;
  int* rnkA = (int*)w; w += (size_t)EA * 4;
  int* offC = (int*)w; w += (size_t)(NN + 1) * 4;
  int* srcC = (int*)w; w += (size_t)EC * 4;
  int* rnkC = (int*)w; w += (size_t)EC * 4;
  uint* Th  = BAh;   // aliases: phases are sequential
  uint* Pdh = BAh;   // tail outputs: BAh,BBh,Peh,Qeh contiguous
  uint* Qdh = BBh;

  hipMemsetAsync(cntA, 0, zero_bytes, stream);

  k_rank<<<1536, 256, 0, stream>>>(EIa + EA, EIc + EC, cntA, cntC, rnkA, rnkC);
  k_scan2<<<2, 1024, 0, stream>>>(cntA, offA, cntC, offC);
  k_place<<<1536, 256, 0, stream>>>(EIa, EIc, offA, rnkA, srcA, offC, rnkC, srcC);

  k_prepw<<<14, 256, 0, stream>>>(gatW, gatA, intW, dw1, ew1, gatWb, intWb, db1, eb1, WT, BIASALL);
  k_nodeinfo<<<(NN + 255) / 256, 256, 0, stream>>>(POS, RAD, Mmet, Mdon, Macc, Mhyd, BATCH, PRAD, MBb);
  k_embed<<<2048, 128, 0, stream>>>(X, embW, Hh);

  int gg = (NN + 127) / 128;
  int nodeGrid = (NN + 15) / 16;
  for (int l = 0; l < 3; ++l){
    // y=0: BAh = Hh@W + Wb ; y=1: BBh = Hh@(W@A) + Wb@A  (independent)
    k_gemm_mfma<false><<<dim3(gg, 2), 256, 0, stream>>>(Hh, WT + (size_t)l * 8192, (size_t)3 * 8192,
                                                        BIASALL + l * 128, (size_t)3 * 128,
                                                        BAh, (size_t)NN * 64, NN);
    k_gat<<<nodeGrid, 256, 0, stream>>>(Hh, BAh, BBh, offA, srcA, gatGw + l * 256, gatGb + l);
  }
  for (int l = 0; l < 3; ++l){
    k_gemm_mfma<true><<<dim3(gg, 1), 256, 0, stream>>>(Hh, WT + (size_t)(6 + l) * 8192, 0,
                                                       BIASALL + (6 + l) * 128, 0, Th, 0, NN);
    k_inter<<<nodeGrid, 256, 0, stream>>>(Hh, Th, offC, srcC, intGw + l * 256, intGb + l);
  }
  // tail: 4 GEMMs fused via blockIdx.y -> Pd,Qd,Pe,Qe
  k_gemm_mfma<false><<<dim3(gg, 4), 256, 0, stream>>>(Hh, WT + (size_t)9 * 8192, (size_t)8192,
                                                      BIASALL + 9 * 128, (size_t)128,
                                                      BAh, (size_t)NN * 64, NN);

  k_edges<<<2048, 256, 0, stream>>>(EIi, PRAD, MBb, Pdh, Qdh, Peh, Qeh,
                                    dw2, db2, ew2, eb2, hbc, hpc,
                                    GENG, out + 512);
  k_final<<<2, 256, 0, stream>>>(GENG, ROT, rcc, out);
}